// Round 13
// baseline (305.806 us; speedup 1.0000x reference)
//
#include <hip/hip_runtime.h>

// LSTM cell fused, round 16: R13 with ONE micro-change -- the four explicit
// "s_waitcnt lgkmcnt(0)" drains before each MFMA cluster are REMOVED.
// Those came from the m201 template where ds_reads are inline-asm
// (compiler-invisible); ours are visible loads, and hipcc emits fine-grained
// counted lgkmcnt(N) between ds_read and first MFMA use on its own (m97
// disasm finding). The manual full drain serialized ~12-read LDS latency
// ahead of every cluster (m141 failure mode: defeating the scheduler).
// Barriers/setprio/vmcnt unchanged (vmcnt IS required: global_load_lds is
// invisible). Everything else byte-identical to the verified 303.9us R13.

#define BDIM 8192
#define KDIM 2048
#define NDIM 1024
#define NCAT 4096
#define NT   32      // K-tiles of 64

typedef __bf16 bf16x8 __attribute__((ext_vector_type(8)));
typedef float  f32x4  __attribute__((ext_vector_type(4)));

__device__ __forceinline__ void async_cp16(const void* g, void* l) {
    __builtin_amdgcn_global_load_lds((__attribute__((address_space(1))) void*)g,
                                     (__attribute__((address_space(3))) void*)l,
                                     16, 0, 0);
}

__device__ __forceinline__ float sigm(float x) { return 1.f / (1.f + __expf(-x)); }
__device__ __forceinline__ float tanh_fast(float x) { return 1.f - 2.f / (1.f + __expf(2.f * x)); }

#define BARM asm volatile("s_barrier" ::: "memory")

// ---------------- prep v3 (R12): transpose-first, fat pack blocks ----------
__global__ __launch_bounds__(256)
void prep_kernel(const float* __restrict__ Z, const float* __restrict__ H,
                 const float* __restrict__ Wi, const float* __restrict__ Wf,
                 const float* __restrict__ Wo, const float* __restrict__ Wg,
                 __bf16* __restrict__ A, __bf16* __restrict__ Wt) {
    __shared__ float t[64][65];
    const int bid = blockIdx.x;
    const int tid = threadIdx.x;

    if (bid < 2048) {
        const int g   = bid >> 9;
        const int rem = bid & 511;
        const int k0  = (rem & 31) * 64;
        const int n0  = (rem >> 5) * 64;
        const float* W = (g == 0) ? Wi : (g == 1) ? Wf : (g == 2) ? Wo : Wg;

        const int c4 = tid & 15, r0 = tid >> 4;
        #pragma unroll
        for (int it = 0; it < 4; ++it) {
            const int r = r0 + it * 16;
            float4 v = ((const float4*)W)[(size_t)(k0 + r) * 256 + (n0 >> 2) + c4];
            t[r][c4 * 4 + 0] = v.x;
            t[r][c4 * 4 + 1] = v.y;
            t[r][c4 * 4 + 2] = v.z;
            t[r][c4 * 4 + 3] = v.w;
        }
        __syncthreads();

        const int kc = tid & 7, nn0 = tid >> 3;
        #pragma unroll
        for (int j = 0; j < 2; ++j) {
            const int n    = nn0 + j * 32;
            const int ncat = n0 + n;
            const size_t outRow = (size_t)(ncat >> 5) * 128 + g * 32 + (ncat & 31);
            bf16x8 o;
            #pragma unroll
            for (int kk = 0; kk < 8; ++kk) o[kk] = (__bf16)t[kc * 8 + kk][n];
            *(bf16x8*)(Wt + outRow * KDIM + k0 + kc * 8) = o;
        }
    } else {
        const bool isZ = (bid < 3072);
        const int base = (bid - (isZ ? 2048 : 3072)) * 1024;
        const float* src = isZ ? Z : H;
        #pragma unroll
        for (int it = 0; it < 4; ++it) {
            const int u   = base + it * 256 + tid;
            const int row = u >> 7;
            const int q8  = u & 127;
            const float4* p = (const float4*)src + ((size_t)row << 8) + q8 * 2;
            float4 v0 = p[0], v1 = p[1];
            bf16x8 o = { (__bf16)v0.x, (__bf16)v0.y, (__bf16)v0.z, (__bf16)v0.w,
                         (__bf16)v1.x, (__bf16)v1.y, (__bf16)v1.z, (__bf16)v1.w };
            const int col8 = isZ ? q8 : (q8 + 128);
            ((bf16x8*)A)[(size_t)row * 256 + col8] = o;
        }
    }
}

// ---------------- 256x256 8-phase GEMM + fused LSTM epilogue ---------------
__global__ __launch_bounds__(512, 2)
void lstm_gemm_kernel(const __bf16* __restrict__ A, const __bf16* __restrict__ Wt,
                      const float* __restrict__ b_i, const float* __restrict__ b_f,
                      const float* __restrict__ b_o, const float* __restrict__ b_g,
                      const float* __restrict__ c_prev, float* __restrict__ out) {
    extern __shared__ char smem[];   // 128KB: buf{0,1} x { A 2x16KB | B 2x16KB }

    const int tid  = threadIdx.x;
    const int wave = tid >> 6;
    const int lane = tid & 63;
    const int wm   = wave >> 2;      // 0..1  (m half: 128 rows each)
    const int wn   = wave & 3;       // 0..3  (64 cat cols each)
    const int l15  = lane & 15;
    const int quad = lane >> 4;

    // XCD swizzle, PANEL-FAST: same-XCD consecutive blocks share the m-tile
    // (A-slice L2-hit) while alternating the XCD's 2 resident Wt panels.
    const int bid   = blockIdx.x;
    const int xcd   = bid & 7;
    const int panel = (bid >> 3) & 1;
    const int by    = bid >> 4;                   // m-tile [0,32)
    const int bxc   = xcd * 2 + panel;            // cat-tile [0,16)
    const int m0   = by * 256;
    const int cat0 = bxc * 256;
    const int n0   = bxc * 64;

    // staging: panel [128][32] = 8KB = 512thr x 16B, 1 load/thread.
    const int srow = tid >> 2;
    const int sgch = (tid & 3) ^ ((tid >> 3) & 3);
    const __bf16* Ags = A  + (size_t)(m0   + srow) * KDIM + sgch * 8;
    const __bf16* Bgs = Wt + (size_t)(cat0 + srow) * KDIM + sgch * 8;
    char* ldsw = smem + wave * 1024;

#define STG(o, h, kt, b) do { \
    const __bf16* gp_ = ((o) ? Bgs : Ags) + (size_t)(h) * 128 * KDIM + (kt) * 64; \
    char* lp_ = ldsw + (b) * 65536 + (o) * 32768 + (h) * 16384; \
    async_cp16(gp_,      lp_); \
    async_cp16(gp_ + 32, lp_ + 8192); \
} while (0)

    // fragment read offsets: row r, k-chunk c -> byte r*64 + (c^((r>>1)&3))*16
    const int swz   = (quad ^ ((l15 >> 1) & 3)) * 16;
    const int abase = wm * 16384 + l15 * 64 + swz;
    const int bbase = 32768 + (wn >> 1) * 16384 + ((wn & 1) * 64 + l15) * 64 + swz;

    f32x4 acc[8][4];
    #pragma unroll
    for (int i = 0; i < 8; ++i)
        #pragma unroll
        for (int j = 0; j < 4; ++j) acc[i][j] = (f32x4){0.f, 0.f, 0.f, 0.f};

    bf16x8 af[4][2];   // current m-quadrant (4 frags x 2 ks)
    bf16x8 bf[4][2];   // all 4 n-frags x 2 ks

    auto LDA = [&](int mh, int bufb) {
        const char* p = smem + bufb + abase + mh * 4096;
        #pragma unroll
        for (int m = 0; m < 4; ++m) {
            af[m][0] = *(const bf16x8*)(p + m * 1024);
            af[m][1] = *(const bf16x8*)(p + m * 1024 + 8192);
        }
    };
    auto LDB = [&](int nh, int bufb) {
        const char* p = smem + bufb + bbase + nh * 2048;
        #pragma unroll
        for (int n = 0; n < 2; ++n) {
            bf[nh * 2 + n][0] = *(const bf16x8*)(p + n * 1024);
            bf[nh * 2 + n][1] = *(const bf16x8*)(p + n * 1024 + 8192);
        }
    };
    auto MMA = [&](int mh, int nh) {
        #pragma unroll
        for (int m = 0; m < 4; ++m)
            #pragma unroll
            for (int n = 0; n < 2; ++n) {
                acc[mh * 4 + m][nh * 2 + n] = __builtin_amdgcn_mfma_f32_16x16x32_bf16(
                    af[m][0], bf[nh * 2 + n][0], acc[mh * 4 + m][nh * 2 + n], 0, 0, 0);
                acc[mh * 4 + m][nh * 2 + n] = __builtin_amdgcn_mfma_f32_16x16x32_bf16(
                    af[m][1], bf[nh * 2 + n][1], acc[mh * 4 + m][nh * 2 + n], 0, 0, 0);
            }
    };

    // ---- prologue: tile0 fully + tile1 h0 halves; keep tile1-h0 in flight
    STG(0, 0, 0, 0); STG(1, 0, 0, 0); STG(0, 1, 0, 0); STG(1, 1, 0, 0);
    STG(0, 0, 1, 1); STG(1, 0, 1, 1);
    asm volatile("s_waitcnt vmcnt(4)" ::: "memory");   // tile0 landed
    BARM;

    #pragma unroll 2
    for (int t = 0; t < NT; ++t) {
        const int b    = t & 1;
        const int bufb = b * 65536;
        // phase 0: quadrant (mh0, nh0); stage (t+1) A-h1 -> other buf.
        // NOTE: no manual lgkmcnt(0) -- ds_reads are compiler-visible; hipcc
        // inserts fine-grained counted waits before first MFMA use (m97).
        LDA(0, bufb); LDB(0, bufb);
        if (t + 1 < NT) STG(0, 1, t + 1, b ^ 1);
        BARM;
        __builtin_amdgcn_s_setprio(1); MMA(0, 0); __builtin_amdgcn_s_setprio(0);
        BARM;
        // phase 1: (mh0, nh1); stage (t+1) B-h1
        LDB(1, bufb);
        if (t + 1 < NT) STG(1, 1, t + 1, b ^ 1);
        BARM;
        __builtin_amdgcn_s_setprio(1); MMA(0, 1); __builtin_amdgcn_s_setprio(0);
        BARM;
        // phase 2: (mh1, nh0); no stage
        LDA(1, bufb);
        BARM;
        __builtin_amdgcn_s_setprio(1); MMA(1, 0); __builtin_amdgcn_s_setprio(0);
        BARM;
        // phase 3: (mh1, nh1); stage (t+2) h0 halves; counted vmcnt publishes t+1
        if (t + 2 < NT) { STG(0, 0, t + 2, b); STG(1, 0, t + 2, b); }
        if (t < NT - 2) { asm volatile("s_waitcnt vmcnt(4)" ::: "memory"); }
        else            { asm volatile("s_waitcnt vmcnt(0)" ::: "memory"); }
        BARM;
        __builtin_amdgcn_s_setprio(1); MMA(1, 1); __builtin_amdgcn_s_setprio(0);
        BARM;
    }

    // ---- epilogue: 4 passes of 64 m-rows; Ep[64][258] f32 (66KB) ----
    float* Ep = (float*)smem;
    const int nn = tid & 63;
    const float bvi = b_i[n0 + nn], bvf = b_f[n0 + nn];
    const float bvo = b_o[n0 + nn], bvg = b_g[n0 + nn];
    int colW[4];
    #pragma unroll
    for (int nt = 0; nt < 4; ++nt)
        colW[nt] = ((wn & 1) * 2 + (nt >> 1)) * 64 + (wn >> 1) * 32 + (nt & 1) * 16 + l15;

    #pragma unroll
    for (int ch = 0; ch < 4; ++ch) {
        // prefetch this chunk's c_prev (nontemporal, read-once); latency
        // hides under the Ep LDS writes + 2 barriers below.
        float cpv[8];
        #pragma unroll
        for (int e = 0; e < 8; ++e) {
            const int row = e * 8 + wave;
            cpv[e] = __builtin_nontemporal_load(
                &c_prev[(size_t)(m0 + ch * 64 + row) * NDIM + n0 + nn]);
        }
        __syncthreads();
        if (wm == (ch >> 1)) {
            #pragma unroll
            for (int mi = 0; mi < 4; ++mi) {
                const int mt = (ch & 1) * 4 + mi;
                #pragma unroll
                for (int nt = 0; nt < 4; ++nt)
                    #pragma unroll
                    for (int r = 0; r < 4; ++r)
                        Ep[(mi * 16 + quad * 4 + r) * 258 + colW[nt]] = acc[mt][nt][r];
            }
        }
        __syncthreads();
        #pragma unroll
        for (int e = 0; e < 8; ++e) {
            const int row = e * 8 + wave;
            const float gi = sigm(Ep[row * 258 + nn] + bvi);
            const float gf = sigm(Ep[row * 258 + 64 + nn] + bvf);
            const float go = sigm(Ep[row * 258 + 128 + nn] + bvo);
            const float gg = tanh_fast(Ep[row * 258 + 192 + nn] + bvg);
            const size_t pos = (size_t)(m0 + ch * 64 + row) * NDIM + n0 + nn;
            const float cv = gf * cpv[e] + gi * gg;
            __builtin_nontemporal_store(go * tanh_fast(cv), &out[pos]);          // h
            __builtin_nontemporal_store(cv, &out[(size_t)BDIM * NDIM + pos]);    // c
        }
    }
#undef STG
}

extern "C" void kernel_launch(void* const* d_in, const int* in_sizes, int n_in,
                              void* d_out, int out_size, void* d_ws, size_t ws_size,
                              hipStream_t stream) {
    const float* Z  = (const float*)d_in[0];
    const float* H  = (const float*)d_in[1];
    const float* Cp = (const float*)d_in[2];
    const float* Wi = (const float*)d_in[3];
    const float* bi = (const float*)d_in[4];
    const float* Wf = (const float*)d_in[5];
    const float* bf = (const float*)d_in[6];
    const float* Wo = (const float*)d_in[7];
    const float* bo = (const float*)d_in[8];
    const float* Wg = (const float*)d_in[9];
    const float* bg = (const float*)d_in[10];

    __bf16* Acomb = (__bf16*)d_ws;                              // 32 MB
    __bf16* Wtp   = (__bf16*)((char*)d_ws + (size_t)33554432);  // 16 MB

    static bool cfg = false;
    if (!cfg) {
        hipFuncSetAttribute(reinterpret_cast<const void*>(lstm_gemm_kernel),
                            hipFuncAttributeMaxDynamicSharedMemorySize, 131072);
        cfg = true;
    }

    prep_kernel<<<4096, 256, 0, stream>>>(Z, H, Wi, Wf, Wo, Wg, Acomb, Wtp);
    lstm_gemm_kernel<<<512, 512, 131072, stream>>>(
        Acomb, Wtp, bi, bf, bo, bg, Cp, (float*)d_out);
}

// Round 14
// 304.189 us; speedup vs baseline: 1.0053x; 1.0053x over previous
//
#include <hip/hip_runtime.h>

// LSTM cell fused, FINAL (round 17): R13 byte-identical restore -- the
// verified session best (303.9us; reproduced 304.4 R15). R16's lgkmcnt
// removal was null-to-negative (158.2 vs 155.5 gemm) -> reverted.
// Measured decomposition: gemm 155.5us (841 TF, 37% MfmaUtil; floor of the
// 4-phase 256x256 family across 5 schedule variants), prep ~45us (3.2 TB/s,
// invariant across 3 rewrites), harness ~104us (fixed; measured via R8
// fusion). Negative ledger: 8-phase, tri-buffer, 32x32x16, depth-3
// prefetch, lgkm discipline, grid-barrier fusion. Wins banked: panel-fast
// XCD order (FETCH 287->164MB), 0-conflict LDS swizzle, counted vmcnt(4),
// setprio, nontemporal epilogue, transpose-first prep.

#define BDIM 8192
#define KDIM 2048
#define NDIM 1024
#define NCAT 4096
#define NT   32      // K-tiles of 64

typedef __bf16 bf16x8 __attribute__((ext_vector_type(8)));
typedef float  f32x4  __attribute__((ext_vector_type(4)));

__device__ __forceinline__ void async_cp16(const void* g, void* l) {
    __builtin_amdgcn_global_load_lds((__attribute__((address_space(1))) void*)g,
                                     (__attribute__((address_space(3))) void*)l,
                                     16, 0, 0);
}

__device__ __forceinline__ float sigm(float x) { return 1.f / (1.f + __expf(-x)); }
__device__ __forceinline__ float tanh_fast(float x) { return 1.f - 2.f / (1.f + __expf(2.f * x)); }

#define BARM asm volatile("s_barrier" ::: "memory")

// ---------------- prep v3: transpose-first, fat pack blocks ----------------
__global__ __launch_bounds__(256)
void prep_kernel(const float* __restrict__ Z, const float* __restrict__ H,
                 const float* __restrict__ Wi, const float* __restrict__ Wf,
                 const float* __restrict__ Wo, const float* __restrict__ Wg,
                 __bf16* __restrict__ A, __bf16* __restrict__ Wt) {
    __shared__ float t[64][65];
    const int bid = blockIdx.x;
    const int tid = threadIdx.x;

    if (bid < 2048) {
        const int g   = bid >> 9;
        const int rem = bid & 511;
        const int k0  = (rem & 31) * 64;
        const int n0  = (rem >> 5) * 64;
        const float* W = (g == 0) ? Wi : (g == 1) ? Wf : (g == 2) ? Wo : Wg;

        const int c4 = tid & 15, r0 = tid >> 4;
        #pragma unroll
        for (int it = 0; it < 4; ++it) {
            const int r = r0 + it * 16;
            float4 v = ((const float4*)W)[(size_t)(k0 + r) * 256 + (n0 >> 2) + c4];
            t[r][c4 * 4 + 0] = v.x;
            t[r][c4 * 4 + 1] = v.y;
            t[r][c4 * 4 + 2] = v.z;
            t[r][c4 * 4 + 3] = v.w;
        }
        __syncthreads();

        const int kc = tid & 7, nn0 = tid >> 3;
        #pragma unroll
        for (int j = 0; j < 2; ++j) {
            const int n    = nn0 + j * 32;
            const int ncat = n0 + n;
            const size_t outRow = (size_t)(ncat >> 5) * 128 + g * 32 + (ncat & 31);
            bf16x8 o;
            #pragma unroll
            for (int kk = 0; kk < 8; ++kk) o[kk] = (__bf16)t[kc * 8 + kk][n];
            *(bf16x8*)(Wt + outRow * KDIM + k0 + kc * 8) = o;
        }
    } else {
        const bool isZ = (bid < 3072);
        const int base = (bid - (isZ ? 2048 : 3072)) * 1024;
        const float* src = isZ ? Z : H;
        #pragma unroll
        for (int it = 0; it < 4; ++it) {
            const int u   = base + it * 256 + tid;
            const int row = u >> 7;
            const int q8  = u & 127;
            const float4* p = (const float4*)src + ((size_t)row << 8) + q8 * 2;
            float4 v0 = p[0], v1 = p[1];
            bf16x8 o = { (__bf16)v0.x, (__bf16)v0.y, (__bf16)v0.z, (__bf16)v0.w,
                         (__bf16)v1.x, (__bf16)v1.y, (__bf16)v1.z, (__bf16)v1.w };
            const int col8 = isZ ? q8 : (q8 + 128);
            ((bf16x8*)A)[(size_t)row * 256 + col8] = o;
        }
    }
}

// ---------------- 256x256 4-phase GEMM + fused LSTM epilogue ---------------
__global__ __launch_bounds__(512, 2)
void lstm_gemm_kernel(const __bf16* __restrict__ A, const __bf16* __restrict__ Wt,
                      const float* __restrict__ b_i, const float* __restrict__ b_f,
                      const float* __restrict__ b_o, const float* __restrict__ b_g,
                      const float* __restrict__ c_prev, float* __restrict__ out) {
    extern __shared__ char smem[];   // 128KB: buf{0,1} x { A 2x16KB | B 2x16KB }

    const int tid  = threadIdx.x;
    const int wave = tid >> 6;
    const int lane = tid & 63;
    const int wm   = wave >> 2;      // 0..1  (m half: 128 rows each)
    const int wn   = wave & 3;       // 0..3  (64 cat cols each)
    const int l15  = lane & 15;
    const int quad = lane >> 4;

    // XCD swizzle, PANEL-FAST: same-XCD consecutive blocks share the m-tile
    // (A-slice L2-hit) while alternating the XCD's 2 resident Wt panels.
    const int bid   = blockIdx.x;
    const int xcd   = bid & 7;
    const int panel = (bid >> 3) & 1;
    const int by    = bid >> 4;                   // m-tile [0,32)
    const int bxc   = xcd * 2 + panel;            // cat-tile [0,16)
    const int m0   = by * 256;
    const int cat0 = bxc * 256;
    const int n0   = bxc * 64;

    // staging: panel [128][32] = 8KB = 512thr x 16B, 1 load/thread.
    const int srow = tid >> 2;
    const int sgch = (tid & 3) ^ ((tid >> 3) & 3);
    const __bf16* Ags = A  + (size_t)(m0   + srow) * KDIM + sgch * 8;
    const __bf16* Bgs = Wt + (size_t)(cat0 + srow) * KDIM + sgch * 8;
    char* ldsw = smem + wave * 1024;

#define STG(o, h, kt, b) do { \
    const __bf16* gp_ = ((o) ? Bgs : Ags) + (size_t)(h) * 128 * KDIM + (kt) * 64; \
    char* lp_ = ldsw + (b) * 65536 + (o) * 32768 + (h) * 16384; \
    async_cp16(gp_,      lp_); \
    async_cp16(gp_ + 32, lp_ + 8192); \
} while (0)

    // fragment read offsets: row r, k-chunk c -> byte r*64 + (c^((r>>1)&3))*16
    const int swz   = (quad ^ ((l15 >> 1) & 3)) * 16;
    const int abase = wm * 16384 + l15 * 64 + swz;
    const int bbase = 32768 + (wn >> 1) * 16384 + ((wn & 1) * 64 + l15) * 64 + swz;

    f32x4 acc[8][4];
    #pragma unroll
    for (int i = 0; i < 8; ++i)
        #pragma unroll
        for (int j = 0; j < 4; ++j) acc[i][j] = (f32x4){0.f, 0.f, 0.f, 0.f};

    bf16x8 af[4][2];   // current m-quadrant (4 frags x 2 ks)
    bf16x8 bf[4][2];   // all 4 n-frags x 2 ks

    auto LDA = [&](int mh, int bufb) {
        const char* p = smem + bufb + abase + mh * 4096;
        #pragma unroll
        for (int m = 0; m < 4; ++m) {
            af[m][0] = *(const bf16x8*)(p + m * 1024);
            af[m][1] = *(const bf16x8*)(p + m * 1024 + 8192);
        }
    };
    auto LDB = [&](int nh, int bufb) {
        const char* p = smem + bufb + bbase + nh * 2048;
        #pragma unroll
        for (int n = 0; n < 2; ++n) {
            bf[nh * 2 + n][0] = *(const bf16x8*)(p + n * 1024);
            bf[nh * 2 + n][1] = *(const bf16x8*)(p + n * 1024 + 8192);
        }
    };
    auto MMA = [&](int mh, int nh) {
        #pragma unroll
        for (int m = 0; m < 4; ++m)
            #pragma unroll
            for (int n = 0; n < 2; ++n) {
                acc[mh * 4 + m][nh * 2 + n] = __builtin_amdgcn_mfma_f32_16x16x32_bf16(
                    af[m][0], bf[nh * 2 + n][0], acc[mh * 4 + m][nh * 2 + n], 0, 0, 0);
                acc[mh * 4 + m][nh * 2 + n] = __builtin_amdgcn_mfma_f32_16x16x32_bf16(
                    af[m][1], bf[nh * 2 + n][1], acc[mh * 4 + m][nh * 2 + n], 0, 0, 0);
            }
    };

    // ---- prologue: tile0 fully + tile1 h0 halves; keep tile1-h0 in flight
    STG(0, 0, 0, 0); STG(1, 0, 0, 0); STG(0, 1, 0, 0); STG(1, 1, 0, 0);
    STG(0, 0, 1, 1); STG(1, 0, 1, 1);
    asm volatile("s_waitcnt vmcnt(4)" ::: "memory");   // tile0 landed
    BARM;

    #pragma unroll 2
    for (int t = 0; t < NT; ++t) {
        const int b    = t & 1;
        const int bufb = b * 65536;
        // phase 0: quadrant (mh0, nh0); stage (t+1) A-h1 -> other buf
        LDA(0, bufb); LDB(0, bufb);
        if (t + 1 < NT) STG(0, 1, t + 1, b ^ 1);
        BARM; asm volatile("s_waitcnt lgkmcnt(0)" ::: "memory");
        __builtin_amdgcn_s_setprio(1); MMA(0, 0); __builtin_amdgcn_s_setprio(0);
        BARM;
        // phase 1: (mh0, nh1); stage (t+1) B-h1
        LDB(1, bufb);
        if (t + 1 < NT) STG(1, 1, t + 1, b ^ 1);
        BARM; asm volatile("s_waitcnt lgkmcnt(0)" ::: "memory");
        __builtin_amdgcn_s_setprio(1); MMA(0, 1); __builtin_amdgcn_s_setprio(0);
        BARM;
        // phase 2: (mh1, nh0); no stage
        LDA(1, bufb);
        BARM; asm volatile("s_waitcnt lgkmcnt(0)" ::: "memory");
        __builtin_amdgcn_s_setprio(1); MMA(1, 0); __builtin_amdgcn_s_setprio(0);
        BARM;
        // phase 3: (mh1, nh1); stage (t+2) h0 halves; counted vmcnt publishes t+1
        if (t + 2 < NT) { STG(0, 0, t + 2, b); STG(1, 0, t + 2, b); }
        if (t < NT - 2) { asm volatile("s_waitcnt vmcnt(4)" ::: "memory"); }
        else            { asm volatile("s_waitcnt vmcnt(0)" ::: "memory"); }
        BARM;
        __builtin_amdgcn_s_setprio(1); MMA(1, 1); __builtin_amdgcn_s_setprio(0);
        BARM;
    }

    // ---- epilogue: 4 passes of 64 m-rows; Ep[64][258] f32 (66KB) ----
    float* Ep = (float*)smem;
    const int nn = tid & 63;
    const float bvi = b_i[n0 + nn], bvf = b_f[n0 + nn];
    const float bvo = b_o[n0 + nn], bvg = b_g[n0 + nn];
    int colW[4];
    #pragma unroll
    for (int nt = 0; nt < 4; ++nt)
        colW[nt] = ((wn & 1) * 2 + (nt >> 1)) * 64 + (wn >> 1) * 32 + (nt & 1) * 16 + l15;

    #pragma unroll
    for (int ch = 0; ch < 4; ++ch) {
        // prefetch this chunk's c_prev (nontemporal, read-once); latency
        // hides under the Ep LDS writes + 2 barriers below.
        float cpv[8];
        #pragma unroll
        for (int e = 0; e < 8; ++e) {
            const int row = e * 8 + wave;
            cpv[e] = __builtin_nontemporal_load(
                &c_prev[(size_t)(m0 + ch * 64 + row) * NDIM + n0 + nn]);
        }
        __syncthreads();
        if (wm == (ch >> 1)) {
            #pragma unroll
            for (int mi = 0; mi < 4; ++mi) {
                const int mt = (ch & 1) * 4 + mi;
                #pragma unroll
                for (int nt = 0; nt < 4; ++nt)
                    #pragma unroll
                    for (int r = 0; r < 4; ++r)
                        Ep[(mi * 16 + quad * 4 + r) * 258 + colW[nt]] = acc[mt][nt][r];
            }
        }
        __syncthreads();
        #pragma unroll
        for (int e = 0; e < 8; ++e) {
            const int row = e * 8 + wave;
            const float gi = sigm(Ep[row * 258 + nn] + bvi);
            const float gf = sigm(Ep[row * 258 + 64 + nn] + bvf);
            const float go = sigm(Ep[row * 258 + 128 + nn] + bvo);
            const float gg = tanh_fast(Ep[row * 258 + 192 + nn] + bvg);
            const size_t pos = (size_t)(m0 + ch * 64 + row) * NDIM + n0 + nn;
            const float cv = gf * cpv[e] + gi * gg;
            __builtin_nontemporal_store(go * tanh_fast(cv), &out[pos]);          // h
            __builtin_nontemporal_store(cv, &out[(size_t)BDIM * NDIM + pos]);    // c
        }
    }
#undef STG
}

extern "C" void kernel_launch(void* const* d_in, const int* in_sizes, int n_in,
                              void* d_out, int out_size, void* d_ws, size_t ws_size,
                              hipStream_t stream) {
    const float* Z  = (const float*)d_in[0];
    const float* H  = (const float*)d_in[1];
    const float* Cp = (const float*)d_in[2];
    const float* Wi = (const float*)d_in[3];
    const float* bi = (const float*)d_in[4];
    const float* Wf = (const float*)d_in[5];
    const float* bf = (const float*)d_in[6];
    const float* Wo = (const float*)d_in[7];
    const float* bo = (const float*)d_in[8];
    const float* Wg = (const float*)d_in[9];
    const float* bg = (const float*)d_in[10];

    __bf16* Acomb = (__bf16*)d_ws;                              // 32 MB
    __bf16* Wtp   = (__bf16*)((char*)d_ws + (size_t)33554432);  // 16 MB

    static bool cfg = false;
    if (!cfg) {
        hipFuncSetAttribute(reinterpret_cast<const void*>(lstm_gemm_kernel),
                            hipFuncAttributeMaxDynamicSharedMemorySize, 131072);
        cfg = true;
    }

    prep_kernel<<<4096, 256, 0, stream>>>(Z, H, Wi, Wf, Wo, Wg, Acomb, Wtp);
    lstm_gemm_kernel<<<512, 512, 131072, stream>>>(
        Acomb, Wtp, bi, bf, bo, bg, Cp, (float*)d_out);
}